// Round 1
// baseline (286686.060 us; speedup 1.0000x reference)
//
#include <hip/hip_runtime.h>
#include <math.h>

namespace {

constexpr int kNU = 100000;
constexpr int kNI = 50000;
constexpr int kDIN = 64;
constexpr int kDH = 128;
constexpr int kL = 2;
constexpr int kNNZ = 5000000;
constexpr float kSlope = 0.2f;
constexpr float kEps = 1e-5f;

// ---------------------------------------------------------------------------
// Input FC: u = leaky(emb[:NU] @ fc_u_w.T + b), i = leaky(emb[NU:] @ fc_i_w.T + b)
// One row per 128-thread block; emb row staged in LDS; W rows read per-thread
// (small, cache-resident). Also writes the accumulator (d_out) initial value.
// ---------------------------------------------------------------------------
__global__ __launch_bounds__(128) void fc_in_kernel(
    const float* __restrict__ emb, const float* __restrict__ wu,
    const float* __restrict__ bu, const float* __restrict__ wi,
    const float* __restrict__ bi, float* __restrict__ ubuf,
    float* __restrict__ ibuf, float* __restrict__ out) {
  const int n = blockIdx.x;       // 0 .. NU+NI-1
  const int d = threadIdx.x;      // 0 .. 127
  __shared__ float e[kDIN];
  if (d < kDIN) e[d] = emb[(size_t)n * kDIN + d];
  __syncthreads();
  const float* W;
  const float* B;
  float* dst;
  int nl;
  if (n < kNU) { W = wu; B = bu; dst = ubuf; nl = n; }
  else         { W = wi; B = bi; dst = ibuf; nl = n - kNU; }
  float s = B[d];
  const float* wr = W + (size_t)d * kDIN;
#pragma unroll
  for (int k = 0; k < kDIN; ++k) s = fmaf(e[k], wr[k], s);
  s = s > 0.f ? s : kSlope * s;
  dst[(size_t)nl * kDH + d] = s;
  out[(size_t)n * kDH + d] = s;
}

// ---------------------------------------------------------------------------
// SpMM scatter (atomic baseline): dst[di[e]] += vals[e] * src[si[e]]
// 8 threads per edge, 16 features each (4x float4 loads + 16 f32 atomics).
// ---------------------------------------------------------------------------
__global__ __launch_bounds__(256) void spmm_atomic_kernel(
    float* __restrict__ dst, const float* __restrict__ src,
    const int* __restrict__ di, const int* __restrict__ si,
    const float* __restrict__ vals) {
  const int gid = blockIdx.x * 256 + threadIdx.x;
  if (gid >= kNNZ * 8) return;
  const int e = gid >> 3;
  const int f = (gid & 7) * 16;
  const float v = vals[e];
  const float* s = src + (size_t)si[e] * kDH + f;
  float* d = dst + (size_t)di[e] * kDH + f;
#pragma unroll
  for (int j = 0; j < 4; ++j) {
    float4 a = *(const float4*)(s + 4 * j);
    atomicAdd(d + 4 * j + 0, v * a.x);
    atomicAdd(d + 4 * j + 1, v * a.y);
    atomicAdd(d + 4 * j + 2, v * a.z);
    atomicAdd(d + 4 * j + 3, v * a.w);
  }
}

// ---------------------------------------------------------------------------
// Fused FC (bias-free) + LayerNorm: out = LN(X @ W.T) * g + b
// W is [DH][DH] row-major (out_d, in_k). Staged transposed+padded in LDS
// (stride 132 floats -> conflict-free float4 reads). 8 rows per 256-thread
// block: thread (r = tid>>5, lanes l=tid&31) computes features 4l..4l+3.
// Row reduction via width-32 shuffles (r is wave-contiguous).
// ---------------------------------------------------------------------------
constexpr int kFclnRows = 8;
constexpr int kWPad = 132;

__global__ __launch_bounds__(256) void fcln_kernel(
    const float* __restrict__ X, const float* __restrict__ W,
    const float* __restrict__ g, const float* __restrict__ b,
    float* __restrict__ out, int N) {
  __shared__ float Wt[kDH * kWPad];          // [k][d], padded
  __shared__ float Xl[kFclnRows][kDH];
  const int tid = threadIdx.x;
  for (int idx = tid; idx < kDH * kDH; idx += 256) {
    const int d = idx >> 7, k = idx & 127;
    Wt[k * kWPad + d] = W[idx];
  }
  const int row0 = blockIdx.x * kFclnRows;
  const int r = tid >> 5;
  const int l = tid & 31;
  {
    const int n = row0 + r;
    float4 xv = make_float4(0.f, 0.f, 0.f, 0.f);
    if (n < N) xv = *(const float4*)(X + (size_t)n * kDH + l * 4);
    *(float4*)(&Xl[r][l * 4]) = xv;
  }
  __syncthreads();
  float4 acc = make_float4(0.f, 0.f, 0.f, 0.f);
  const int d0 = l * 4;
#pragma unroll 4
  for (int k = 0; k < kDH; ++k) {
    const float x = Xl[r][k];
    const float4 w = *(const float4*)(&Wt[k * kWPad + d0]);
    acc.x = fmaf(x, w.x, acc.x);
    acc.y = fmaf(x, w.y, acc.y);
    acc.z = fmaf(x, w.z, acc.z);
    acc.w = fmaf(x, w.w, acc.w);
  }
  float s = acc.x + acc.y + acc.z + acc.w;
  float sq = acc.x * acc.x + acc.y * acc.y + acc.z * acc.z + acc.w * acc.w;
#pragma unroll
  for (int m = 16; m >= 1; m >>= 1) {
    s += __shfl_xor(s, m, 32);
    sq += __shfl_xor(sq, m, 32);
  }
  const float mu = s * (1.f / kDH);
  const float var = sq * (1.f / kDH) - mu * mu;
  const float rs = 1.f / sqrtf(var + kEps);
  const int n = row0 + r;
  if (n < N) {
    const float4 gg = *(const float4*)(g + d0);
    const float4 bb = *(const float4*)(b + d0);
    float4 o;
    o.x = (acc.x - mu) * rs * gg.x + bb.x;
    o.y = (acc.y - mu) * rs * gg.y + bb.y;
    o.z = (acc.z - mu) * rs * gg.z + bb.z;
    o.w = (acc.w - mu) * rs * gg.w + bb.w;
    *(float4*)(out + (size_t)n * kDH + d0) = o;
  }
}

// ---------------------------------------------------------------------------
// h = leaky(LN(T) * g + b); upd += h; acc += h
// One wave (64 lanes) per row, 2 features per lane.
// ---------------------------------------------------------------------------
__global__ __launch_bounds__(256) void leaky_ln_kernel(
    const float* __restrict__ T, const float* __restrict__ g,
    const float* __restrict__ b, float* __restrict__ upd,
    float* __restrict__ acc, int N) {
  const int wid = threadIdx.x >> 6;
  const int lane = threadIdx.x & 63;
  const int n = blockIdx.x * 4 + wid;
  if (n >= N) return;
  const int d = lane * 2;
  const float2 v = *(const float2*)(T + (size_t)n * kDH + d);
  float s = v.x + v.y;
  float sq = v.x * v.x + v.y * v.y;
#pragma unroll
  for (int m = 32; m >= 1; m >>= 1) {
    s += __shfl_xor(s, m, 64);
    sq += __shfl_xor(sq, m, 64);
  }
  const float mu = s * (1.f / kDH);
  const float var = sq * (1.f / kDH) - mu * mu;
  const float rs = 1.f / sqrtf(var + kEps);
  const float2 gg = *(const float2*)(g + d);
  const float2 bb = *(const float2*)(b + d);
  float hx = (v.x - mu) * rs * gg.x + bb.x;
  float hy = (v.y - mu) * rs * gg.y + bb.y;
  hx = hx > 0.f ? hx : kSlope * hx;
  hy = hy > 0.f ? hy : kSlope * hy;
  float2 uv = *(const float2*)(upd + (size_t)n * kDH + d);
  uv.x += hx;
  uv.y += hy;
  *(float2*)(upd + (size_t)n * kDH + d) = uv;
  float2 av = *(const float2*)(acc + (size_t)n * kDH + d);
  av.x += hx;
  av.y += hy;
  *(float2*)(acc + (size_t)n * kDH + d) = av;
}

__global__ __launch_bounds__(256) void scale_kernel(float* __restrict__ p,
                                                    float sc, int n4) {
  const int gid = blockIdx.x * 256 + threadIdx.x;
  if (gid < n4) {
    float4 v = ((float4*)p)[gid];
    v.x *= sc; v.y *= sc; v.z *= sc; v.w *= sc;
    ((float4*)p)[gid] = v;
  }
}

}  // namespace

extern "C" void kernel_launch(void* const* d_in, const int* in_sizes, int n_in,
                              void* d_out, int out_size, void* d_ws,
                              size_t ws_size, hipStream_t stream) {
  const float* emb    = (const float*)d_in[0];
  const float* fc_u_w = (const float*)d_in[1];
  const float* fc_u_b = (const float*)d_in[2];
  const float* fc_i_w = (const float*)d_in[3];
  const float* fc_i_b = (const float*)d_in[4];
  const float* vals   = (const float*)d_in[5];
  const float* Wu     = (const float*)d_in[6];
  const float* ln1g_u = (const float*)d_in[7];
  const float* ln1b_u = (const float*)d_in[8];
  const float* ln2g_u = (const float*)d_in[9];
  const float* ln2b_u = (const float*)d_in[10];
  const float* Wi     = (const float*)d_in[11];
  const float* ln1g_i = (const float*)d_in[12];
  const float* ln1b_i = (const float*)d_in[13];
  const float* ln2g_i = (const float*)d_in[14];
  const float* ln2b_i = (const float*)d_in[15];
  const int*   rows   = (const int*)d_in[16];
  const int*   cols   = (const int*)d_in[17];
  float* out = (float*)d_out;

  // Workspace layout (floats): u[NU*DH] | i[NI*DH] | T1[NU*DH] | T2[NU*DH]
  float* u    = (float*)d_ws;
  float* ibuf = u + (size_t)kNU * kDH;
  float* T1   = ibuf + (size_t)kNI * kDH;
  float* T2   = T1 + (size_t)kNU * kDH;

  fc_in_kernel<<<kNU + kNI, 128, 0, stream>>>(emb, fc_u_w, fc_u_b, fc_i_w,
                                              fc_i_b, u, ibuf, out);

  const int spmm_grid = (kNNZ * 8 + 255) / 256;
  for (int k = 0; k < kL; ++k) {
    const float* Wuk = Wu + (size_t)k * kDH * kDH;
    const float* Wik = Wi + (size_t)k * kDH * kDH;
    // ---- hu: y1[cols] += v*u[rows]; lat1 = LN(y1@Wu.T); y2[rows] += v*lat1[cols]
    hipMemsetAsync(T1, 0, (size_t)kNI * kDH * sizeof(float), stream);
    spmm_atomic_kernel<<<spmm_grid, 256, 0, stream>>>(T1, u, cols, rows, vals);
    fcln_kernel<<<(kNI + kFclnRows - 1) / kFclnRows, 256, 0, stream>>>(
        T1, Wuk, ln1g_u + k * kDH, ln1b_u + k * kDH, T2, kNI);
    hipMemsetAsync(T1, 0, (size_t)kNU * kDH * sizeof(float), stream);
    spmm_atomic_kernel<<<spmm_grid, 256, 0, stream>>>(T1, T2, rows, cols, vals);
    leaky_ln_kernel<<<(kNU + 3) / 4, 256, 0, stream>>>(
        T1, ln2g_u + k * kDH, ln2b_u + k * kDH, u, out, kNU);
    // ---- hi: y1[rows] += v*i[cols]; lat1 = LN(y1@Wi.T); y2[cols] += v*lat1[rows]
    hipMemsetAsync(T2, 0, (size_t)kNU * kDH * sizeof(float), stream);
    spmm_atomic_kernel<<<spmm_grid, 256, 0, stream>>>(T2, ibuf, rows, cols, vals);
    fcln_kernel<<<(kNU + kFclnRows - 1) / kFclnRows, 256, 0, stream>>>(
        T2, Wik, ln1g_i + k * kDH, ln1b_i + k * kDH, T1, kNU);
    hipMemsetAsync(T2, 0, (size_t)kNI * kDH * sizeof(float), stream);
    spmm_atomic_kernel<<<spmm_grid, 256, 0, stream>>>(T2, T1, cols, rows, vals);
    leaky_ln_kernel<<<(kNI + 3) / 4, 256, 0, stream>>>(
        T2, ln2g_i + k * kDH, ln2b_i + k * kDH, ibuf, out + (size_t)kNU * kDH,
        kNI);
  }
  const int n4 = (kNU + kNI) * kDH / 4;
  scale_kernel<<<(n4 + 255) / 256, 256, 0, stream>>>(out, 1.f / (kL + 1), n4);
}

// Round 2
// 4792.899 us; speedup vs baseline: 59.8147x; 59.8147x over previous
//
#include <hip/hip_runtime.h>
#include <math.h>

namespace {

constexpr int kNU = 100000;
constexpr int kNI = 50000;
constexpr int kDIN = 64;
constexpr int kDH = 128;
constexpr int kL = 2;
constexpr int kNNZ = 5000000;
constexpr float kSlope = 0.2f;
constexpr float kEps = 1e-5f;

constexpr int kNSeg = kNU + kNI;       // combined row+col segment count
constexpr int kScanTile = 2048;        // 256 threads x 8 items
constexpr int kScanBlocks = (kNSeg + kScanTile - 1) / kScanTile;  // 74

struct alignas(8) Edge { int idx; float val; };

// ---------------------------------------------------------------------------
// Input FC: u = leaky(emb[:NU] @ fc_u_w.T + b), i = leaky(emb[NU:] @ fc_i_w.T + b)
// ---------------------------------------------------------------------------
__global__ __launch_bounds__(128) void fc_in_kernel(
    const float* __restrict__ emb, const float* __restrict__ wu,
    const float* __restrict__ bu, const float* __restrict__ wi,
    const float* __restrict__ bi, float* __restrict__ ubuf,
    float* __restrict__ ibuf, float* __restrict__ out) {
  const int n = blockIdx.x;
  const int d = threadIdx.x;
  __shared__ float e[kDIN];
  if (d < kDIN) e[d] = emb[(size_t)n * kDIN + d];
  __syncthreads();
  const float* W;
  const float* B;
  float* dst;
  int nl;
  if (n < kNU) { W = wu; B = bu; dst = ubuf; nl = n; }
  else         { W = wi; B = bi; dst = ibuf; nl = n - kNU; }
  float s = B[d];
  const float* wr = W + (size_t)d * kDIN;
#pragma unroll
  for (int k = 0; k < kDIN; ++k) s = fmaf(e[k], wr[k], s);
  s = s > 0.f ? s : kSlope * s;
  dst[(size_t)nl * kDH + d] = s;
  out[(size_t)n * kDH + d] = s;
}

// ---------------------------------------------------------------------------
// Adjacency build: histogram -> exclusive scan -> position scatter
// cnt[0..NU) = row degrees, cnt[NU..NU+NI) = col degrees. Combined scan puts
// CSR and CSC contiguously in one edge buffer of 2*NNZ records.
// ---------------------------------------------------------------------------
__global__ __launch_bounds__(256) void hist_kernel(
    const int* __restrict__ rows, const int* __restrict__ cols,
    int* __restrict__ cnt) {
  const int e = blockIdx.x * 256 + threadIdx.x;
  if (e >= kNNZ) return;
  atomicAdd(&cnt[rows[e]], 1);
  atomicAdd(&cnt[kNU + cols[e]], 1);
}

__global__ __launch_bounds__(256) void scan_partial_kernel(
    const int* __restrict__ in, int* __restrict__ out, int* __restrict__ bsum,
    int N) {
  __shared__ int sdata[256];
  const int tid = threadIdx.x;
  const int base = blockIdx.x * kScanTile + tid * 8;
  int v[8];
  int s = 0;
#pragma unroll
  for (int j = 0; j < 8; ++j) {
    v[j] = (base + j < N) ? in[base + j] : 0;
    s += v[j];
  }
  sdata[tid] = s;
  __syncthreads();
#pragma unroll
  for (int off = 1; off < 256; off <<= 1) {
    int t = (tid >= off) ? sdata[tid - off] : 0;
    __syncthreads();
    sdata[tid] += t;
    __syncthreads();
  }
  int run = sdata[tid] - s;  // exclusive prefix of this thread
#pragma unroll
  for (int j = 0; j < 8; ++j) {
    if (base + j < N) out[base + j] = run;
    run += v[j];
  }
  if (tid == 255) bsum[blockIdx.x] = sdata[255];
}

__global__ __launch_bounds__(256) void scan_bsums_kernel(int* __restrict__ bsum,
                                                         int M) {
  __shared__ int sd[256];
  const int tid = threadIdx.x;
  const int v = (tid < M) ? bsum[tid] : 0;
  sd[tid] = v;
  __syncthreads();
#pragma unroll
  for (int off = 1; off < 256; off <<= 1) {
    int t = (tid >= off) ? sd[tid - off] : 0;
    __syncthreads();
    sd[tid] += t;
    __syncthreads();
  }
  if (tid < M) bsum[tid] = sd[tid] - v;  // exclusive
}

__global__ __launch_bounds__(256) void scan_add_kernel(
    int* __restrict__ out, const int* __restrict__ bsum, int N) {
  const int i = blockIdx.x * 256 + threadIdx.x;
  if (i < N) out[i] += bsum[i / kScanTile];
  if (i == 0) out[N] = 2 * kNNZ;
}

__global__ __launch_bounds__(256) void scatter_kernel(
    const int* __restrict__ rows, const int* __restrict__ cols,
    const float* __restrict__ vals, int* __restrict__ cur,
    Edge* __restrict__ edges) {
  const int e = blockIdx.x * 256 + threadIdx.x;
  if (e >= kNNZ) return;
  const int r = rows[e];
  const int c = cols[e];
  const float v = vals[e];
  const int p = atomicAdd(&cur[r], 1);          // CSR: segment r, gather idx=c
  *(int2*)&edges[p] = make_int2(c, __float_as_int(v));
  const int q = atomicAdd(&cur[kNU + c], 1);    // CSC: segment c, gather idx=r
  *(int2*)&edges[q] = make_int2(r, __float_as_int(v));
}

// ---------------------------------------------------------------------------
// Gather SpMM: dst[n] = sum_{e in seg(n)} edges[e].val * src[edges[e].idx]
// One wave per output row, float2 per lane (64 lanes x 2 = 128 feats).
// Edge records are wave-uniform loads (L1 broadcast); gathers are 512B/row
// coalesced across the wave.
// ---------------------------------------------------------------------------
__global__ __launch_bounds__(256) void spmm_gather_kernel(
    float* __restrict__ dst, const float* __restrict__ src,
    const int* __restrict__ ptr, const Edge* __restrict__ edges, int N) {
  const int wid = threadIdx.x >> 6;
  const int lane = threadIdx.x & 63;
  const int n = blockIdx.x * 4 + wid;
  if (n >= N) return;
  const int d = lane * 2;
  int e = ptr[n];
  const int e1 = ptr[n + 1];
  float2 acc = make_float2(0.f, 0.f);
  for (; e + 4 <= e1; e += 4) {
    const Edge r0 = edges[e + 0];
    const Edge r1 = edges[e + 1];
    const Edge r2 = edges[e + 2];
    const Edge r3 = edges[e + 3];
    const float2 s0 = *(const float2*)(src + (size_t)r0.idx * kDH + d);
    const float2 s1 = *(const float2*)(src + (size_t)r1.idx * kDH + d);
    const float2 s2 = *(const float2*)(src + (size_t)r2.idx * kDH + d);
    const float2 s3 = *(const float2*)(src + (size_t)r3.idx * kDH + d);
    acc.x = fmaf(r0.val, s0.x, acc.x); acc.y = fmaf(r0.val, s0.y, acc.y);
    acc.x = fmaf(r1.val, s1.x, acc.x); acc.y = fmaf(r1.val, s1.y, acc.y);
    acc.x = fmaf(r2.val, s2.x, acc.x); acc.y = fmaf(r2.val, s2.y, acc.y);
    acc.x = fmaf(r3.val, s3.x, acc.x); acc.y = fmaf(r3.val, s3.y, acc.y);
  }
  for (; e < e1; ++e) {
    const Edge r = edges[e];
    const float2 s = *(const float2*)(src + (size_t)r.idx * kDH + d);
    acc.x = fmaf(r.val, s.x, acc.x);
    acc.y = fmaf(r.val, s.y, acc.y);
  }
  *(float2*)(dst + (size_t)n * kDH + d) = acc;
}

// ---------------------------------------------------------------------------
// Fused FC (bias-free) + LayerNorm: out = LN(X @ W.T) * g + b
// ---------------------------------------------------------------------------
constexpr int kFclnRows = 8;
constexpr int kWPad = 132;

__global__ __launch_bounds__(256) void fcln_kernel(
    const float* __restrict__ X, const float* __restrict__ W,
    const float* __restrict__ g, const float* __restrict__ b,
    float* __restrict__ out, int N) {
  __shared__ float Wt[kDH * kWPad];  // [k][d], padded
  __shared__ float Xl[kFclnRows][kDH];
  const int tid = threadIdx.x;
  for (int idx = tid; idx < kDH * kDH; idx += 256) {
    const int d = idx >> 7, k = idx & 127;
    Wt[k * kWPad + d] = W[idx];
  }
  const int row0 = blockIdx.x * kFclnRows;
  const int r = tid >> 5;
  const int l = tid & 31;
  {
    const int n = row0 + r;
    float4 xv = make_float4(0.f, 0.f, 0.f, 0.f);
    if (n < N) xv = *(const float4*)(X + (size_t)n * kDH + l * 4);
    *(float4*)(&Xl[r][l * 4]) = xv;
  }
  __syncthreads();
  float4 acc = make_float4(0.f, 0.f, 0.f, 0.f);
  const int d0 = l * 4;
#pragma unroll 4
  for (int k = 0; k < kDH; ++k) {
    const float x = Xl[r][k];
    const float4 w = *(const float4*)(&Wt[k * kWPad + d0]);
    acc.x = fmaf(x, w.x, acc.x);
    acc.y = fmaf(x, w.y, acc.y);
    acc.z = fmaf(x, w.z, acc.z);
    acc.w = fmaf(x, w.w, acc.w);
  }
  float s = acc.x + acc.y + acc.z + acc.w;
  float sq = acc.x * acc.x + acc.y * acc.y + acc.z * acc.z + acc.w * acc.w;
#pragma unroll
  for (int m = 16; m >= 1; m >>= 1) {
    s += __shfl_xor(s, m, 32);
    sq += __shfl_xor(sq, m, 32);
  }
  const float mu = s * (1.f / kDH);
  const float var = sq * (1.f / kDH) - mu * mu;
  const float rs = 1.f / sqrtf(var + kEps);
  const int n = row0 + r;
  if (n < N) {
    const float4 gg = *(const float4*)(g + d0);
    const float4 bb = *(const float4*)(b + d0);
    float4 o;
    o.x = (acc.x - mu) * rs * gg.x + bb.x;
    o.y = (acc.y - mu) * rs * gg.y + bb.y;
    o.z = (acc.z - mu) * rs * gg.z + bb.z;
    o.w = (acc.w - mu) * rs * gg.w + bb.w;
    *(float4*)(out + (size_t)n * kDH + d0) = o;
  }
}

// ---------------------------------------------------------------------------
// h = leaky(LN(T) * g + b); upd += h; acc += h
// ---------------------------------------------------------------------------
__global__ __launch_bounds__(256) void leaky_ln_kernel(
    const float* __restrict__ T, const float* __restrict__ g,
    const float* __restrict__ b, float* __restrict__ upd,
    float* __restrict__ acc, int N) {
  const int wid = threadIdx.x >> 6;
  const int lane = threadIdx.x & 63;
  const int n = blockIdx.x * 4 + wid;
  if (n >= N) return;
  const int d = lane * 2;
  const float2 v = *(const float2*)(T + (size_t)n * kDH + d);
  float s = v.x + v.y;
  float sq = v.x * v.x + v.y * v.y;
#pragma unroll
  for (int m = 32; m >= 1; m >>= 1) {
    s += __shfl_xor(s, m, 64);
    sq += __shfl_xor(sq, m, 64);
  }
  const float mu = s * (1.f / kDH);
  const float var = sq * (1.f / kDH) - mu * mu;
  const float rs = 1.f / sqrtf(var + kEps);
  const float2 gg = *(const float2*)(g + d);
  const float2 bb = *(const float2*)(b + d);
  float hx = (v.x - mu) * rs * gg.x + bb.x;
  float hy = (v.y - mu) * rs * gg.y + bb.y;
  hx = hx > 0.f ? hx : kSlope * hx;
  hy = hy > 0.f ? hy : kSlope * hy;
  float2 uv = *(const float2*)(upd + (size_t)n * kDH + d);
  uv.x += hx;
  uv.y += hy;
  *(float2*)(upd + (size_t)n * kDH + d) = uv;
  float2 av = *(const float2*)(acc + (size_t)n * kDH + d);
  av.x += hx;
  av.y += hy;
  *(float2*)(acc + (size_t)n * kDH + d) = av;
}

__global__ __launch_bounds__(256) void scale_kernel(float* __restrict__ p,
                                                    float sc, int n4) {
  const int gid = blockIdx.x * 256 + threadIdx.x;
  if (gid < n4) {
    float4 v = ((float4*)p)[gid];
    v.x *= sc; v.y *= sc; v.z *= sc; v.w *= sc;
    ((float4*)p)[gid] = v;
  }
}

}  // namespace

extern "C" void kernel_launch(void* const* d_in, const int* in_sizes, int n_in,
                              void* d_out, int out_size, void* d_ws,
                              size_t ws_size, hipStream_t stream) {
  const float* emb    = (const float*)d_in[0];
  const float* fc_u_w = (const float*)d_in[1];
  const float* fc_u_b = (const float*)d_in[2];
  const float* fc_i_w = (const float*)d_in[3];
  const float* fc_i_b = (const float*)d_in[4];
  const float* vals   = (const float*)d_in[5];
  const float* Wu     = (const float*)d_in[6];
  const float* ln1g_u = (const float*)d_in[7];
  const float* ln1b_u = (const float*)d_in[8];
  const float* ln2g_u = (const float*)d_in[9];
  const float* ln2b_u = (const float*)d_in[10];
  const float* Wi     = (const float*)d_in[11];
  const float* ln1g_i = (const float*)d_in[12];
  const float* ln1b_i = (const float*)d_in[13];
  const float* ln2g_i = (const float*)d_in[14];
  const float* ln2b_i = (const float*)d_in[15];
  const int*   rows   = (const int*)d_in[16];
  const int*   cols   = (const int*)d_in[17];
  float* out = (float*)d_out;

  // Workspace: u | i | T1 | T2 | edges[2*NNZ] | cnt | ptr | cur | bsum
  float* u    = (float*)d_ws;
  float* ibuf = u + (size_t)kNU * kDH;
  float* T1   = ibuf + (size_t)kNI * kDH;
  float* T2   = T1 + (size_t)kNU * kDH;
  Edge*  edges = (Edge*)(T2 + (size_t)kNU * kDH);
  int*   cnt  = (int*)(edges + (size_t)2 * kNNZ);
  int*   ptr  = cnt + kNSeg;        // kNSeg+1 entries
  int*   cur  = ptr + kNSeg + 1;    // kNSeg+1 entries
  int*   bsum = cur + kNSeg + 1;    // kScanBlocks entries

  const int egrid = (kNNZ + 255) / 256;

  // ---- adjacency build ----
  hipMemsetAsync(cnt, 0, (size_t)kNSeg * sizeof(int), stream);
  hist_kernel<<<egrid, 256, 0, stream>>>(rows, cols, cnt);
  scan_partial_kernel<<<kScanBlocks, 256, 0, stream>>>(cnt, ptr, bsum, kNSeg);
  scan_bsums_kernel<<<1, 256, 0, stream>>>(bsum, kScanBlocks);
  scan_add_kernel<<<(kNSeg + 255) / 256, 256, 0, stream>>>(ptr, bsum, kNSeg);
  hipMemcpyAsync(cur, ptr, (size_t)(kNSeg + 1) * sizeof(int),
                 hipMemcpyDeviceToDevice, stream);
  scatter_kernel<<<egrid, 256, 0, stream>>>(rows, cols, vals, cur, edges);

  // ---- input FC ----
  fc_in_kernel<<<kNU + kNI, 128, 0, stream>>>(emb, fc_u_w, fc_u_b, fc_i_w,
                                              fc_i_b, u, ibuf, out);

  for (int k = 0; k < kL; ++k) {
    const float* Wuk = Wu + (size_t)k * kDH * kDH;
    const float* Wik = Wi + (size_t)k * kDH * kDH;
    // ---- hu ----
    spmm_gather_kernel<<<(kNI + 3) / 4, 256, 0, stream>>>(T1, u, ptr + kNU,
                                                          edges, kNI);
    fcln_kernel<<<(kNI + kFclnRows - 1) / kFclnRows, 256, 0, stream>>>(
        T1, Wuk, ln1g_u + k * kDH, ln1b_u + k * kDH, T2, kNI);
    spmm_gather_kernel<<<(kNU + 3) / 4, 256, 0, stream>>>(T1, T2, ptr, edges,
                                                          kNU);
    leaky_ln_kernel<<<(kNU + 3) / 4, 256, 0, stream>>>(
        T1, ln2g_u + k * kDH, ln2b_u + k * kDH, u, out, kNU);
    // ---- hi ----
    spmm_gather_kernel<<<(kNU + 3) / 4, 256, 0, stream>>>(T2, ibuf, ptr, edges,
                                                          kNU);
    fcln_kernel<<<(kNU + kFclnRows - 1) / kFclnRows, 256, 0, stream>>>(
        T2, Wik, ln1g_i + k * kDH, ln1b_i + k * kDH, T1, kNU);
    spmm_gather_kernel<<<(kNI + 3) / 4, 256, 0, stream>>>(T2, T1, ptr + kNU,
                                                          edges, kNI);
    leaky_ln_kernel<<<(kNI + 3) / 4, 256, 0, stream>>>(
        T2, ln2g_i + k * kDH, ln2b_i + k * kDH, ibuf, out + (size_t)kNU * kDH,
        kNI);
  }
  const int n4 = (kNU + kNI) * kDH / 4;
  scale_kernel<<<(n4 + 255) / 256, 256, 0, stream>>>(out, 1.f / (kL + 1), n4);
}

// Round 3
// 3473.682 us; speedup vs baseline: 82.5309x; 1.3798x over previous
//
#include <hip/hip_runtime.h>
#include <math.h>

namespace {

constexpr int kNU = 100000;
constexpr int kNI = 50000;
constexpr int kDIN = 64;
constexpr int kDH = 128;
constexpr int kDH2 = kDH / 2;          // u32 (bf16x2) per feature row
constexpr int kNNZ = 5000000;
constexpr float kSlope = 0.2f;
constexpr float kEps = 1e-5f;

constexpr int kNSeg = kNU + kNI;
constexpr int kScanTile = 2048;
constexpr int kScanBlocks = (kNSeg + kScanTile - 1) / kScanTile;

struct alignas(8) Edge { int idx; float val; };

// ---- bf16x2 <-> f32 helpers (RNE pack) ----
__device__ inline float2 bf2f(uint p) {
  return make_float2(__uint_as_float(p << 16),
                     __uint_as_float(p & 0xffff0000u));
}
__device__ inline uint f2bf1(float f) {
  const uint a = __float_as_uint(f);
  return (a + 0x7fffu + ((a >> 16) & 1u)) >> 16;
}
__device__ inline uint f2bf(float2 v) {
  return f2bf1(v.x) | (f2bf1(v.y) << 16);
}

// ---------------------------------------------------------------------------
// Input FC -> bf16 state buffers + f32 accumulator (d_out)
// ---------------------------------------------------------------------------
__global__ __launch_bounds__(128) void fc_in_kernel(
    const float* __restrict__ emb, const float* __restrict__ wu,
    const float* __restrict__ bu, const float* __restrict__ wi,
    const float* __restrict__ bi, uint* __restrict__ ubuf,
    uint* __restrict__ ibuf, float* __restrict__ out) {
  const int n = blockIdx.x;
  const int d = threadIdx.x;
  __shared__ float e[kDIN];
  __shared__ float sh[kDH];
  if (d < kDIN) e[d] = emb[(size_t)n * kDIN + d];
  __syncthreads();
  const float* W;
  const float* B;
  uint* dst;
  int nl;
  if (n < kNU) { W = wu; B = bu; dst = ubuf; nl = n; }
  else         { W = wi; B = bi; dst = ibuf; nl = n - kNU; }
  float s = B[d];
  const float* wr = W + (size_t)d * kDIN;
#pragma unroll
  for (int k = 0; k < kDIN; ++k) s = fmaf(e[k], wr[k], s);
  s = s > 0.f ? s : kSlope * s;
  sh[d] = s;
  out[(size_t)n * kDH + d] = s;
  __syncthreads();
  if (d < kDH2)
    dst[(size_t)nl * kDH2 + d] = f2bf(make_float2(sh[2 * d], sh[2 * d + 1]));
}

// ---------------------------------------------------------------------------
// Adjacency build (histogram -> scan -> scatter), unchanged from R1
// ---------------------------------------------------------------------------
__global__ __launch_bounds__(256) void hist_kernel(
    const int* __restrict__ rows, const int* __restrict__ cols,
    int* __restrict__ cnt) {
  const int e = blockIdx.x * 256 + threadIdx.x;
  if (e >= kNNZ) return;
  atomicAdd(&cnt[rows[e]], 1);
  atomicAdd(&cnt[kNU + cols[e]], 1);
}

__global__ __launch_bounds__(256) void scan_partial_kernel(
    const int* __restrict__ in, int* __restrict__ out, int* __restrict__ bsum,
    int N) {
  __shared__ int sdata[256];
  const int tid = threadIdx.x;
  const int base = blockIdx.x * kScanTile + tid * 8;
  int v[8];
  int s = 0;
#pragma unroll
  for (int j = 0; j < 8; ++j) {
    v[j] = (base + j < N) ? in[base + j] : 0;
    s += v[j];
  }
  sdata[tid] = s;
  __syncthreads();
#pragma unroll
  for (int off = 1; off < 256; off <<= 1) {
    int t = (tid >= off) ? sdata[tid - off] : 0;
    __syncthreads();
    sdata[tid] += t;
    __syncthreads();
  }
  int run = sdata[tid] - s;
#pragma unroll
  for (int j = 0; j < 8; ++j) {
    if (base + j < N) out[base + j] = run;
    run += v[j];
  }
  if (tid == 255) bsum[blockIdx.x] = sdata[255];
}

__global__ __launch_bounds__(256) void scan_bsums_kernel(int* __restrict__ bsum,
                                                         int M) {
  __shared__ int sd[256];
  const int tid = threadIdx.x;
  const int v = (tid < M) ? bsum[tid] : 0;
  sd[tid] = v;
  __syncthreads();
#pragma unroll
  for (int off = 1; off < 256; off <<= 1) {
    int t = (tid >= off) ? sd[tid - off] : 0;
    __syncthreads();
    sd[tid] += t;
    __syncthreads();
  }
  if (tid < M) bsum[tid] = sd[tid] - v;
}

__global__ __launch_bounds__(256) void scan_add_kernel(
    int* __restrict__ out, const int* __restrict__ bsum, int N) {
  const int i = blockIdx.x * 256 + threadIdx.x;
  if (i < N) out[i] += bsum[i / kScanTile];
  if (i == 0) out[N] = 2 * kNNZ;
}

__global__ __launch_bounds__(256) void scatter_kernel(
    const int* __restrict__ rows, const int* __restrict__ cols,
    const float* __restrict__ vals, int* __restrict__ cur,
    Edge* __restrict__ edges) {
  const int e = blockIdx.x * 256 + threadIdx.x;
  if (e >= kNNZ) return;
  const int r = rows[e];
  const int c = cols[e];
  const float v = vals[e];
  const int p = atomicAdd(&cur[r], 1);
  *(int2*)&edges[p] = make_int2(c, __float_as_int(v));
  const int q = atomicAdd(&cur[kNU + c], 1);
  *(int2*)&edges[q] = make_int2(r, __float_as_int(v));
}

// ---------------------------------------------------------------------------
// Gather SpMM (bf16 src/dst, f32 accumulate). One wave per output row,
// one bf16x2 word (2 feats) per lane. Single- and dual-source variants;
// dual shares one edge-list traversal between two independent SpMMs.
// ---------------------------------------------------------------------------
__global__ __launch_bounds__(256) void spmm_g1_kernel(
    uint* __restrict__ dst, const uint* __restrict__ src,
    const int* __restrict__ ptr, const Edge* __restrict__ edges, int N) {
  const int wid = threadIdx.x >> 6;
  const int lane = threadIdx.x & 63;
  const int n = blockIdx.x * 4 + wid;
  if (n >= N) return;
  int e = ptr[n];
  const int e1 = ptr[n + 1];
  float2 acc = make_float2(0.f, 0.f);
  for (; e + 4 <= e1; e += 4) {
    const Edge r0 = edges[e + 0];
    const Edge r1 = edges[e + 1];
    const Edge r2 = edges[e + 2];
    const Edge r3 = edges[e + 3];
    const float2 s0 = bf2f(src[(size_t)r0.idx * kDH2 + lane]);
    const float2 s1 = bf2f(src[(size_t)r1.idx * kDH2 + lane]);
    const float2 s2 = bf2f(src[(size_t)r2.idx * kDH2 + lane]);
    const float2 s3 = bf2f(src[(size_t)r3.idx * kDH2 + lane]);
    acc.x = fmaf(r0.val, s0.x, acc.x); acc.y = fmaf(r0.val, s0.y, acc.y);
    acc.x = fmaf(r1.val, s1.x, acc.x); acc.y = fmaf(r1.val, s1.y, acc.y);
    acc.x = fmaf(r2.val, s2.x, acc.x); acc.y = fmaf(r2.val, s2.y, acc.y);
    acc.x = fmaf(r3.val, s3.x, acc.x); acc.y = fmaf(r3.val, s3.y, acc.y);
  }
  for (; e < e1; ++e) {
    const Edge r = edges[e];
    const float2 s = bf2f(src[(size_t)r.idx * kDH2 + lane]);
    acc.x = fmaf(r.val, s.x, acc.x);
    acc.y = fmaf(r.val, s.y, acc.y);
  }
  dst[(size_t)n * kDH2 + lane] = f2bf(acc);
}

__global__ __launch_bounds__(256) void spmm_g2_kernel(
    uint* __restrict__ dstA, const uint* __restrict__ srcA,
    uint* __restrict__ dstB, const uint* __restrict__ srcB,
    const int* __restrict__ ptr, const Edge* __restrict__ edges, int N) {
  const int wid = threadIdx.x >> 6;
  const int lane = threadIdx.x & 63;
  const int n = blockIdx.x * 4 + wid;
  if (n >= N) return;
  int e = ptr[n];
  const int e1 = ptr[n + 1];
  float2 aA = make_float2(0.f, 0.f);
  float2 aB = make_float2(0.f, 0.f);
  for (; e + 4 <= e1; e += 4) {
    const Edge r0 = edges[e + 0];
    const Edge r1 = edges[e + 1];
    const Edge r2 = edges[e + 2];
    const Edge r3 = edges[e + 3];
    const float2 a0 = bf2f(srcA[(size_t)r0.idx * kDH2 + lane]);
    const float2 b0 = bf2f(srcB[(size_t)r0.idx * kDH2 + lane]);
    const float2 a1 = bf2f(srcA[(size_t)r1.idx * kDH2 + lane]);
    const float2 b1 = bf2f(srcB[(size_t)r1.idx * kDH2 + lane]);
    const float2 a2 = bf2f(srcA[(size_t)r2.idx * kDH2 + lane]);
    const float2 b2 = bf2f(srcB[(size_t)r2.idx * kDH2 + lane]);
    const float2 a3 = bf2f(srcA[(size_t)r3.idx * kDH2 + lane]);
    const float2 b3 = bf2f(srcB[(size_t)r3.idx * kDH2 + lane]);
    aA.x = fmaf(r0.val, a0.x, aA.x); aA.y = fmaf(r0.val, a0.y, aA.y);
    aB.x = fmaf(r0.val, b0.x, aB.x); aB.y = fmaf(r0.val, b0.y, aB.y);
    aA.x = fmaf(r1.val, a1.x, aA.x); aA.y = fmaf(r1.val, a1.y, aA.y);
    aB.x = fmaf(r1.val, b1.x, aB.x); aB.y = fmaf(r1.val, b1.y, aB.y);
    aA.x = fmaf(r2.val, a2.x, aA.x); aA.y = fmaf(r2.val, a2.y, aA.y);
    aB.x = fmaf(r2.val, b2.x, aB.x); aB.y = fmaf(r2.val, b2.y, aB.y);
    aA.x = fmaf(r3.val, a3.x, aA.x); aA.y = fmaf(r3.val, a3.y, aA.y);
    aB.x = fmaf(r3.val, b3.x, aB.x); aB.y = fmaf(r3.val, b3.y, aB.y);
  }
  for (; e < e1; ++e) {
    const Edge r = edges[e];
    const float2 a = bf2f(srcA[(size_t)r.idx * kDH2 + lane]);
    const float2 b = bf2f(srcB[(size_t)r.idx * kDH2 + lane]);
    aA.x = fmaf(r.val, a.x, aA.x); aA.y = fmaf(r.val, a.y, aA.y);
    aB.x = fmaf(r.val, b.x, aB.x); aB.y = fmaf(r.val, b.y, aB.y);
  }
  dstA[(size_t)n * kDH2 + lane] = f2bf(aA);
  dstB[(size_t)n * kDH2 + lane] = f2bf(aB);
}

// ---------------------------------------------------------------------------
// Fused FC (bias-free) + LayerNorm, bf16 in/out, f32 math.
// ---------------------------------------------------------------------------
constexpr int kFclnRows = 8;
constexpr int kWPad = 132;

__global__ __launch_bounds__(256) void fcln_kernel(
    const uint* __restrict__ X, const float* __restrict__ W,
    const float* __restrict__ g, const float* __restrict__ b,
    uint* __restrict__ out, int N) {
  __shared__ float Wt[kDH * kWPad];
  __shared__ float Xl[kFclnRows][kDH];
  const int tid = threadIdx.x;
  for (int idx = tid; idx < kDH * kDH; idx += 256) {
    const int d = idx >> 7, k = idx & 127;
    Wt[k * kWPad + d] = W[idx];
  }
  const int row0 = blockIdx.x * kFclnRows;
  const int r = tid >> 5;
  const int l = tid & 31;
  {
    const int n = row0 + r;
    uint2 xv = make_uint2(0u, 0u);
    if (n < N) xv = *(const uint2*)(X + (size_t)n * kDH2 + l * 2);
    const float2 p0 = bf2f(xv.x);
    const float2 p1 = bf2f(xv.y);
    Xl[r][l * 4 + 0] = p0.x;
    Xl[r][l * 4 + 1] = p0.y;
    Xl[r][l * 4 + 2] = p1.x;
    Xl[r][l * 4 + 3] = p1.y;
  }
  __syncthreads();
  float4 acc = make_float4(0.f, 0.f, 0.f, 0.f);
  const int d0 = l * 4;
#pragma unroll 4
  for (int k = 0; k < kDH; ++k) {
    const float x = Xl[r][k];
    const float4 w = *(const float4*)(&Wt[k * kWPad + d0]);
    acc.x = fmaf(x, w.x, acc.x);
    acc.y = fmaf(x, w.y, acc.y);
    acc.z = fmaf(x, w.z, acc.z);
    acc.w = fmaf(x, w.w, acc.w);
  }
  float s = acc.x + acc.y + acc.z + acc.w;
  float sq = acc.x * acc.x + acc.y * acc.y + acc.z * acc.z + acc.w * acc.w;
#pragma unroll
  for (int m = 16; m >= 1; m >>= 1) {
    s += __shfl_xor(s, m, 32);
    sq += __shfl_xor(sq, m, 32);
  }
  const float mu = s * (1.f / kDH);
  const float var = sq * (1.f / kDH) - mu * mu;
  const float rs = 1.f / sqrtf(var + kEps);
  const int n = row0 + r;
  if (n < N) {
    const float4 gg = *(const float4*)(g + d0);
    const float4 bb = *(const float4*)(b + d0);
    float2 o0, o1;
    o0.x = (acc.x - mu) * rs * gg.x + bb.x;
    o0.y = (acc.y - mu) * rs * gg.y + bb.y;
    o1.x = (acc.z - mu) * rs * gg.z + bb.z;
    o1.y = (acc.w - mu) * rs * gg.w + bb.w;
    *(uint2*)(out + (size_t)n * kDH2 + l * 2) = make_uint2(f2bf(o0), f2bf(o1));
  }
}

// ---------------------------------------------------------------------------
// h = leaky(LN(T)*g+b); upd(bf16) += h; acc(f32, d_out) += h
// ---------------------------------------------------------------------------
__global__ __launch_bounds__(256) void leaky_ln_kernel(
    const uint* __restrict__ T, const float* __restrict__ g,
    const float* __restrict__ b, uint* __restrict__ upd,
    float* __restrict__ acc, int N) {
  const int wid = threadIdx.x >> 6;
  const int lane = threadIdx.x & 63;
  const int n = blockIdx.x * 4 + wid;
  if (n >= N) return;
  const float2 v = bf2f(T[(size_t)n * kDH2 + lane]);
  float s = v.x + v.y;
  float sq = v.x * v.x + v.y * v.y;
#pragma unroll
  for (int m = 32; m >= 1; m >>= 1) {
    s += __shfl_xor(s, m, 64);
    sq += __shfl_xor(sq, m, 64);
  }
  const float mu = s * (1.f / kDH);
  const float var = sq * (1.f / kDH) - mu * mu;
  const float rs = 1.f / sqrtf(var + kEps);
  const int d = lane * 2;
  const float2 gg = *(const float2*)(g + d);
  const float2 bb = *(const float2*)(b + d);
  float hx = (v.x - mu) * rs * gg.x + bb.x;
  float hy = (v.y - mu) * rs * gg.y + bb.y;
  hx = hx > 0.f ? hx : kSlope * hx;
  hy = hy > 0.f ? hy : kSlope * hy;
  float2 uv = bf2f(upd[(size_t)n * kDH2 + lane]);
  uv.x += hx;
  uv.y += hy;
  upd[(size_t)n * kDH2 + lane] = f2bf(uv);
  float2 av = *(const float2*)(acc + (size_t)n * kDH + d);
  av.x += hx;
  av.y += hy;
  *(float2*)(acc + (size_t)n * kDH + d) = av;
}

__global__ __launch_bounds__(256) void scale_kernel(float* __restrict__ p,
                                                    float sc, int n4) {
  const int gid = blockIdx.x * 256 + threadIdx.x;
  if (gid < n4) {
    float4 v = ((float4*)p)[gid];
    v.x *= sc; v.y *= sc; v.z *= sc; v.w *= sc;
    ((float4*)p)[gid] = v;
  }
}

}  // namespace

extern "C" void kernel_launch(void* const* d_in, const int* in_sizes, int n_in,
                              void* d_out, int out_size, void* d_ws,
                              size_t ws_size, hipStream_t stream) {
  const float* emb    = (const float*)d_in[0];
  const float* fc_u_w = (const float*)d_in[1];
  const float* fc_u_b = (const float*)d_in[2];
  const float* fc_i_w = (const float*)d_in[3];
  const float* fc_i_b = (const float*)d_in[4];
  const float* vals   = (const float*)d_in[5];
  const float* Wu     = (const float*)d_in[6];
  const float* ln1g_u = (const float*)d_in[7];
  const float* ln1b_u = (const float*)d_in[8];
  const float* ln2g_u = (const float*)d_in[9];
  const float* ln2b_u = (const float*)d_in[10];
  const float* Wi     = (const float*)d_in[11];
  const float* ln1g_i = (const float*)d_in[12];
  const float* ln1b_i = (const float*)d_in[13];
  const float* ln2g_i = (const float*)d_in[14];
  const float* ln2b_i = (const float*)d_in[15];
  const int*   rows   = (const int*)d_in[16];
  const int*   cols   = (const int*)d_in[17];
  float* out = (float*)d_out;

  // Workspace (all bf16 feature buffers sized for NU rows):
  // bufU | bufI | P | Q | R | edges[2*NNZ] | cnt | ptr | cur | bsum
  uint* bufU = (uint*)d_ws;
  uint* bufI = bufU + (size_t)kNU * kDH2;
  uint* P    = bufI + (size_t)kNI * kDH2;
  uint* Q    = P + (size_t)kNU * kDH2;
  uint* R    = Q + (size_t)kNU * kDH2;
  Edge* edges = (Edge*)(R + (size_t)kNU * kDH2);
  int*  cnt  = (int*)(edges + (size_t)2 * kNNZ);
  int*  ptr  = cnt + kNSeg;
  int*  cur  = ptr + kNSeg + 1;
  int*  bsum = cur + kNSeg + 1;

  const int egrid = (kNNZ + 255) / 256;
  const int gridU = (kNU + 3) / 4;
  const int gridI = (kNI + 3) / 4;
  const int fgridU = (kNU + kFclnRows - 1) / kFclnRows;
  const int fgridI = (kNI + kFclnRows - 1) / kFclnRows;

  // ---- adjacency build ----
  hipMemsetAsync(cnt, 0, (size_t)kNSeg * sizeof(int), stream);
  hist_kernel<<<egrid, 256, 0, stream>>>(rows, cols, cnt);
  scan_partial_kernel<<<kScanBlocks, 256, 0, stream>>>(cnt, ptr, bsum, kNSeg);
  scan_bsums_kernel<<<1, 256, 0, stream>>>(bsum, kScanBlocks);
  scan_add_kernel<<<(kNSeg + 255) / 256, 256, 0, stream>>>(ptr, bsum, kNSeg);
  hipMemcpyAsync(cur, ptr, (size_t)(kNSeg + 1) * sizeof(int),
                 hipMemcpyDeviceToDevice, stream);
  scatter_kernel<<<egrid, 256, 0, stream>>>(rows, cols, vals, cur, edges);

  // ---- input FC ----
  fc_in_kernel<<<kNU + kNI, 128, 0, stream>>>(emb, fc_u_w, fc_u_b, fc_i_w,
                                              fc_i_b, bufU, bufI, out);

  // ---- layer 0 ----
  // K1: y1_u(L0) over CSC, src = u0
  spmm_g1_kernel<<<gridI, 256, 0, stream>>>(P, bufU, ptr + kNU, edges, kNI);
  fcln_kernel<<<fgridI, 256, 0, stream>>>(P, Wu, ln1g_u, ln1b_u, Q, kNI);
  // K2 (dual, CSR): y2_u(L0) src Q ; y1_i(L0) src i0
  spmm_g2_kernel<<<gridU, 256, 0, stream>>>(P, Q, R, bufI, ptr, edges, kNU);
  leaky_ln_kernel<<<gridU, 256, 0, stream>>>(P, ln2g_u, ln2b_u, bufU, out, kNU);
  fcln_kernel<<<fgridU, 256, 0, stream>>>(R, Wi, ln1g_i, ln1b_i, Q, kNU);
  // K3 (dual, CSC): y2_i(L0) src Q ; y1_u(L1) src u1 (bufU updated above)
  spmm_g2_kernel<<<gridI, 256, 0, stream>>>(P, Q, R, bufU, ptr + kNU, edges,
                                            kNI);
  leaky_ln_kernel<<<gridI, 256, 0, stream>>>(P, ln2g_i, ln2b_i, bufI,
                                             out + (size_t)kNU * kDH, kNI);
  // ---- layer 1 ----
  fcln_kernel<<<fgridI, 256, 0, stream>>>(R, Wu + kDH * kDH, ln1g_u + kDH,
                                          ln1b_u + kDH, Q, kNI);
  // K4 (dual, CSR): y2_u(L1) src Q ; y1_i(L1) src i1 (bufI updated above)
  spmm_g2_kernel<<<gridU, 256, 0, stream>>>(P, Q, R, bufI, ptr, edges, kNU);
  leaky_ln_kernel<<<gridU, 256, 0, stream>>>(P, ln2g_u + kDH, ln2b_u + kDH,
                                             bufU, out, kNU);
  fcln_kernel<<<fgridU, 256, 0, stream>>>(R, Wi + kDH * kDH, ln1g_i + kDH,
                                          ln1b_i + kDH, Q, kNU);
  // K5: y2_i(L1) over CSC, src Q
  spmm_g1_kernel<<<gridI, 256, 0, stream>>>(P, Q, ptr + kNU, edges, kNI);
  leaky_ln_kernel<<<gridI, 256, 0, stream>>>(P, ln2g_i + kDH, ln2b_i + kDH,
                                             bufI, out + (size_t)kNU * kDH,
                                             kNI);

  const int n4 = (kNU + kNI) * kDH / 4;
  scale_kernel<<<(n4 + 255) / 256, 256, 0, stream>>>(out, 1.f / 3.f, n4);
}